// Round 1
// baseline (266.607 us; speedup 1.0000x reference)
//
#include <hip/hip_runtime.h>
#include <math.h>

// Problem constants
#define BSZ 64
#define SEQ 1024
#define HID 1024
#define DOUT 1024
#define SPLIT 8            // s-chunks per batch
#define CHUNK (SEQ/SPLIT)  // 128 rows per block
#define SUB 16             // online-softmax subtile rows

// ws layout (in floats)
//  concatT  [2048][64]      @ 0        (rows 0..1023 = ctx^T, 1024..2047 = hidden^T)
//  x        [64][1024]      @ 131072
//  scoresG  [1024][64]      @ 196608   (raw masked scores, [s][b])
//  ctx_part [64][8][1024]   @ 262144
//  ml_part  [64][8][2]      @ 786432
//  mlfinal  [64][2]         @ 787456
// total 787584 floats = ~3.0 MiB

__global__ void k_transpose_hidden(const float* __restrict__ hidden,
                                   float* __restrict__ concatT) {
    int idx = blockIdx.x * 256 + threadIdx.x;   // 65536 total
    int b = idx >> 10, k = idx & 1023;
    concatT[(HID + k) * BSZ + b] = hidden[idx];
}

// x[b][c] = sum_k hidden[b][k] * W1[c][k]; lane = b, wave handles 4 cols
__global__ __launch_bounds__(256) void k_gemm_x(const float* __restrict__ W1,
                                                const float* __restrict__ concatT,
                                                float* __restrict__ x) {
    __shared__ float tile[256 * 64];  // 64 KiB: k-tile of hidden^T
    int t = threadIdx.x, lane = t & 63, wave = t >> 6;
    int c_base = blockIdx.x * 16;
    float acc[4] = {0.f, 0.f, 0.f, 0.f};
    const float* hT = concatT + HID * BSZ;  // hidden^T rows
    for (int k0 = 0; k0 < HID; k0 += 256) {
        __syncthreads();
        const float4* src = (const float4*)(hT + k0 * BSZ);
        float4* dst = (float4*)tile;
        for (int i = t; i < 4096; i += 256) dst[i] = src[i];
        __syncthreads();
        for (int k = 0; k < 256; ++k) {
            float v = tile[k * 64 + lane];
            int kg = k0 + k;
#pragma unroll
            for (int oi = 0; oi < 4; ++oi) {
                int c = c_base + (wave << 2) + oi;
                acc[oi] += W1[c * HID + kg] * v;
            }
        }
    }
#pragma unroll
    for (int oi = 0; oi < 4; ++oi) {
        int c = c_base + (wave << 2) + oi;
        x[lane * HID + c] = acc[oi];
    }
}

// Fused: scores + mask + online softmax + ctx partial accumulation.
// Grid (SPLIT, BSZ); block 256 = 4 waves. One HBM pass over enc; PV re-read hits L2.
__global__ __launch_bounds__(256) void k_score(const float* __restrict__ enc,
                                               const float* __restrict__ x,
                                               const int* __restrict__ src_lens,
                                               float* __restrict__ scoresG,
                                               float* __restrict__ ctx_part,
                                               float* __restrict__ ml_part) {
    int b = blockIdx.y, chunk = blockIdx.x;
    int t = threadIdx.x, lane = t & 63, wave = t >> 6;
    __shared__ float4 xl[256];   // x[b][:] as float4
    __shared__ float sc[SUB];
    __shared__ float p[SUB];
    const float4* x4 = (const float4*)(x + b * HID);
    xl[t] = x4[t];
    int len = src_lens[b];
    int s0 = chunk * CHUNK;
    float m_run = -3.0e38f, l_run = 0.f;
    float4 acc = {0.f, 0.f, 0.f, 0.f};
    const float* encb = enc + ((long)b << 20);   // b * SEQ * DOUT
    __syncthreads();

    for (int sub = 0; sub < CHUNK / SUB; ++sub) {
        int sbase = s0 + sub * SUB;
        // Phase A: wave w computes rows r = w*4 + j (16 rows total)
#pragma unroll
        for (int j = 0; j < 4; ++j) {
            int r = (wave << 2) + j;
            int s = sbase + r;
            const float4* row4 = (const float4*)(encb + (long)s * DOUT);
            float d = 0.f;
#pragma unroll
            for (int i = 0; i < 4; ++i) {
                float4 e = row4[i * 64 + lane];
                float4 xv = xl[i * 64 + lane];
                d += e.x * xv.x + e.y * xv.y + e.z * xv.z + e.w * xv.w;
            }
#pragma unroll
            for (int off = 32; off > 0; off >>= 1) d += __shfl_xor(d, off, 64);
            if (lane == 0) {
                float val = (s < len) ? d : 0.f;
                if (val == 0.f) val = -1.0e10f;   // mask AND exact-zero rule
                sc[r] = val;
                scoresG[s * BSZ + b] = val;
            }
        }
        __syncthreads();
        // Phase B: subtile max, rescale, p = exp(sc - m_new)
        float msub = sc[0];
#pragma unroll
        for (int r = 1; r < SUB; ++r) msub = fmaxf(msub, sc[r]);
        float m_new = fmaxf(m_run, msub);
        float scale = expf(m_run - m_new);   // first iter: exp(-inf)=0
        if (t < SUB) p[t] = expf(sc[t] - m_new);
        acc.x *= scale; acc.y *= scale; acc.z *= scale; acc.w *= scale;
        __syncthreads();
        float lsub = 0.f;
#pragma unroll
        for (int r = 0; r < SUB; ++r) lsub += p[r];
        l_run = l_run * scale + lsub;
        m_run = m_new;
        // Phase C: acc[d] += sum_r p[r] * enc[s][d]  (re-read from L2, 64 KiB back)
        const float4* c4 = (const float4*)(encb + (long)sbase * DOUT);
#pragma unroll 4
        for (int r = 0; r < SUB; ++r) {
            float pr = p[r];
            float4 e = c4[r * 256 + t];
            acc.x += pr * e.x; acc.y += pr * e.y;
            acc.z += pr * e.z; acc.w += pr * e.w;
        }
        // no barrier needed here: next Phase A only writes sc, whose readers
        // all passed the p-barrier above; next p-write is behind next barrier.
    }

    float4* cp = (float4*)(ctx_part + ((size_t)(b * SPLIT + chunk) << 10));
    cp[t] = acc;
    if (t == 0) {
        ml_part[(b * SPLIT + chunk) * 2]     = m_run;
        ml_part[(b * SPLIT + chunk) * 2 + 1] = l_run;
    }
}

// Combine SPLIT partials per batch; write ctx^T into concatT rows 0..1023.
__global__ __launch_bounds__(256) void k_reduce(const float* __restrict__ ctx_part,
                                                const float* __restrict__ ml_part,
                                                float* __restrict__ concatT,
                                                float* __restrict__ mlfinal) {
    int b = blockIdx.x, t = threadIdx.x;
    float M = -3.0e38f;
#pragma unroll
    for (int c = 0; c < SPLIT; ++c) M = fmaxf(M, ml_part[(b * SPLIT + c) * 2]);
    float w[SPLIT];
    float L = 0.f;
#pragma unroll
    for (int c = 0; c < SPLIT; ++c) {
        float e = expf(ml_part[(b * SPLIT + c) * 2] - M);
        w[c] = e;
        L += ml_part[(b * SPLIT + c) * 2 + 1] * e;
    }
    float4 acc = {0.f, 0.f, 0.f, 0.f};
#pragma unroll
    for (int c = 0; c < SPLIT; ++c) {
        const float4* cp = (const float4*)(ctx_part + ((size_t)(b * SPLIT + c) << 10));
        float4 v = cp[t];
        acc.x += w[c] * v.x; acc.y += w[c] * v.y;
        acc.z += w[c] * v.z; acc.w += w[c] * v.w;
    }
    float inv = 1.f / L;
    int d = t * 4;
    concatT[(d + 0) * BSZ + b] = acc.x * inv;
    concatT[(d + 1) * BSZ + b] = acc.y * inv;
    concatT[(d + 2) * BSZ + b] = acc.z * inv;
    concatT[(d + 3) * BSZ + b] = acc.w * inv;
    if (t == 0) { mlfinal[b * 2] = M; mlfinal[b * 2 + 1] = L; }
}

__global__ void k_attn(const float* __restrict__ scoresG,
                       const float* __restrict__ mlfinal,
                       float* __restrict__ outAttn) {
    int idx = blockIdx.x * 256 + threadIdx.x;  // 65536 total, [s][b]
    int b = idx & 63;
    float M = mlfinal[b * 2], L = mlfinal[b * 2 + 1];
    outAttn[idx] = expf(scoresG[idx] - M) / L;
}

// out[b][o] = tanh( sum_{k<2048} concat[b][k] * W2[o][k] ); lane = b.
__global__ __launch_bounds__(256) void k_out(const float* __restrict__ W2,
                                             const float* __restrict__ concatT,
                                             float* __restrict__ out) {
    __shared__ float tile[256 * 64];
    int t = threadIdx.x, lane = t & 63, wave = t >> 6;
    int o_base = blockIdx.x * 16;
    float acc[4] = {0.f, 0.f, 0.f, 0.f};
    for (int k0 = 0; k0 < HID + DOUT; k0 += 256) {
        __syncthreads();
        const float4* src = (const float4*)(concatT + k0 * BSZ);
        float4* dst = (float4*)tile;
        for (int i = t; i < 4096; i += 256) dst[i] = src[i];
        __syncthreads();
        for (int k = 0; k < 256; ++k) {
            float v = tile[k * 64 + lane];
            int kg = k0 + k;
#pragma unroll
            for (int oi = 0; oi < 4; ++oi) {
                int o = o_base + (wave << 2) + oi;
                acc[oi] += W2[o * (HID + DOUT) + kg] * v;
            }
        }
    }
#pragma unroll
    for (int oi = 0; oi < 4; ++oi) {
        int o = o_base + (wave << 2) + oi;
        out[lane * DOUT + o] = tanhf(acc[oi]);
    }
}

extern "C" void kernel_launch(void* const* d_in, const int* in_sizes, int n_in,
                              void* d_out, int out_size, void* d_ws, size_t ws_size,
                              hipStream_t stream) {
    const float* hidden   = (const float*)d_in[0];
    const float* enc      = (const float*)d_in[1];
    const int*   src_lens = (const int*)d_in[2];
    const float* W1       = (const float*)d_in[3];
    const float* W2       = (const float*)d_in[4];
    float* out     = (float*)d_out;        // [64][1024]
    float* outAttn = out + 65536;          // [1024][64]

    float* ws       = (float*)d_ws;
    float* concatT  = ws;                  // [2048][64]
    float* x        = ws + 131072;         // [64][1024]
    float* scoresG  = ws + 196608;         // [1024][64]
    float* ctx_part = ws + 262144;         // [64][8][1024]
    float* ml_part  = ws + 786432;         // [64][8][2]
    float* mlfinal  = ws + 787456;         // [64][2]

    k_transpose_hidden<<<256, 256, 0, stream>>>(hidden, concatT);
    k_gemm_x<<<64, 256, 0, stream>>>(W1, concatT, x);
    k_score<<<dim3(SPLIT, BSZ), 256, 0, stream>>>(enc, x, src_lens, scoresG, ctx_part, ml_part);
    k_reduce<<<BSZ, 256, 0, stream>>>(ctx_part, ml_part, concatT, mlfinal);
    k_attn<<<256, 256, 0, stream>>>(scoresG, mlfinal, outAttn);
    k_out<<<64, 256, 0, stream>>>(W2, concatT, out);
}

// Round 2
// 100.170 us; speedup vs baseline: 2.6615x; 2.6615x over previous
//
#include <hip/hip_runtime.h>
#include <math.h>

// Problem constants
#define BSZ 64
#define SEQ 1024
#define HID 1024
#define DOUT 1024
#define SPLIT 16           // s-chunks per batch  -> 1024 blocks for k_score
#define CHUNK (SEQ/SPLIT)  // 64 rows per block
#define SUB 16             // online-softmax subtile rows
#define KS1 8              // K-splits for x GEMM   (1024/128)
#define KS2 16             // K-splits for out GEMM (2048/128)

// ws layout (floats):
//  concatT  [2048][64]       @ 0         (rows 0..1023 ctx^T, 1024..2047 hidden^T)
//  x        [64][1024]       @ 131072
//  scoresG  [1024][64]       @ 196608
//  ctx_part [64][16][1024]   @ 262144
//  ml_part  [64][16][2]      @ 1310720
//  mlfinal  [64][2]          @ 1312768
//  xpart    [8][64][1024]    @ 1312896
//  outpart  [16][64][1024]   @ 1837184
// total 2885760 floats ~= 11 MiB

__global__ void k_transpose_hidden(const float* __restrict__ hidden,
                                   float* __restrict__ concatT) {
    int idx = blockIdx.x * 256 + threadIdx.x;   // 65536
    int b = idx >> 10, k = idx & 1023;
    concatT[(HID + k) * BSZ + b] = hidden[idx];
}

// Partial x GEMM: grid (64 colgroups, KS1). Block computes 16 cols x 64 b over a 128-k chunk.
__global__ __launch_bounds__(256) void k_gemm_x_part(const float* __restrict__ W1,
                                                     const float* __restrict__ concatT,
                                                     float* __restrict__ xpart) {
    __shared__ float tile[128 * 64];  // 32 KiB
    int t = threadIdx.x, lane = t & 63, wave = t >> 6;
    int k0 = blockIdx.y * 128;
    int c_base = blockIdx.x * 16 + (wave << 2);
    const float* hT = concatT + HID * BSZ;
    {
        const float4* src = (const float4*)(hT + k0 * BSZ);
        float4* dst = (float4*)tile;
#pragma unroll
        for (int i = 0; i < 8; ++i) dst[t + i * 256] = src[t + i * 256];
    }
    __syncthreads();
    float acc[4] = {0.f, 0.f, 0.f, 0.f};
    for (int k = 0; k < 128; k += 4) {
        float v0 = tile[(k + 0) * 64 + lane];
        float v1 = tile[(k + 1) * 64 + lane];
        float v2 = tile[(k + 2) * 64 + lane];
        float v3 = tile[(k + 3) * 64 + lane];
#pragma unroll
        for (int oi = 0; oi < 4; ++oi) {
            float4 w = *(const float4*)&W1[(c_base + oi) * HID + k0 + k];
            acc[oi] += w.x * v0 + w.y * v1 + w.z * v2 + w.w * v3;
        }
    }
#pragma unroll
    for (int oi = 0; oi < 4; ++oi)
        xpart[((size_t)blockIdx.y * 64 + lane) * 1024 + c_base + oi] = acc[oi];
}

__global__ void k_x_reduce(const float* __restrict__ xpart, float* __restrict__ x) {
    int idx = blockIdx.x * 256 + threadIdx.x;  // 65536: b*1024 + c
    float s = 0.f;
#pragma unroll
    for (int ks = 0; ks < KS1; ++ks) s += xpart[(size_t)ks * 65536 + idx];
    x[idx] = s;
}

// Fused scores + mask + online softmax + ctx partials. Subtile held in registers.
__global__ __launch_bounds__(256) void k_score(const float* __restrict__ enc,
                                               const float* __restrict__ x,
                                               const int* __restrict__ src_lens,
                                               float* __restrict__ scoresG,
                                               float* __restrict__ ctx_part,
                                               float* __restrict__ ml_part) {
    int b = blockIdx.y, chunk = blockIdx.x;
    int t = threadIdx.x, lane = t & 63, wave = t >> 6;
    __shared__ float4 xl[256];          // x[b][:]
    __shared__ float sc[SUB];
    __shared__ float p[SUB];
    __shared__ float4 accbuf[4 * 256];  // 16 KiB cross-wave reduce
    xl[t] = ((const float4*)(x + b * HID))[t];
    int len = src_lens[b];
    int s0 = chunk * CHUNK;
    float m_run = -3.0e38f, l_run = 0.f;
    float4 acc[4];
#pragma unroll
    for (int i = 0; i < 4; ++i) acc[i] = float4{0.f, 0.f, 0.f, 0.f};
    const float* encb = enc + ((long)b << 20);
    __syncthreads();

    for (int sub = 0; sub < CHUNK / SUB; ++sub) {
        int sbase = s0 + sub * SUB;
        float4 e[4][4];
        // Phase A: wave w loads rows r = w*4+j into registers, computes dots
#pragma unroll
        for (int j = 0; j < 4; ++j) {
            int s = sbase + (wave << 2) + j;
            const float4* row4 = (const float4*)(encb + (long)s * DOUT);
#pragma unroll
            for (int i = 0; i < 4; ++i) e[j][i] = row4[i * 64 + lane];
        }
        float d[4];
#pragma unroll
        for (int j = 0; j < 4; ++j) {
            float dd = 0.f;
#pragma unroll
            for (int i = 0; i < 4; ++i) {
                float4 xv = xl[i * 64 + lane];
                dd += e[j][i].x * xv.x + e[j][i].y * xv.y + e[j][i].z * xv.z + e[j][i].w * xv.w;
            }
            d[j] = dd;
        }
#pragma unroll
        for (int off = 32; off > 0; off >>= 1) {
            d[0] += __shfl_xor(d[0], off, 64);
            d[1] += __shfl_xor(d[1], off, 64);
            d[2] += __shfl_xor(d[2], off, 64);
            d[3] += __shfl_xor(d[3], off, 64);
        }
        if (lane == 0) {
#pragma unroll
            for (int j = 0; j < 4; ++j) {
                int r = (wave << 2) + j;
                int s = sbase + r;
                float val = (s < len) ? d[j] : 0.f;
                if (val == 0.f) val = -1.0e10f;   // mask AND exact-zero rule
                sc[r] = val;
                scoresG[s * BSZ + b] = val;
            }
        }
        __syncthreads();
        // Phase B
        float msub = sc[0];
#pragma unroll
        for (int r = 1; r < SUB; ++r) msub = fmaxf(msub, sc[r]);
        float m_new = fmaxf(m_run, msub);
        float scale = expf(m_run - m_new);
        if (t < SUB) p[t] = expf(sc[t] - m_new);
#pragma unroll
        for (int i = 0; i < 4; ++i) {
            acc[i].x *= scale; acc[i].y *= scale; acc[i].z *= scale; acc[i].w *= scale;
        }
        __syncthreads();
        float lsub = 0.f;
#pragma unroll
        for (int r = 0; r < SUB; ++r) lsub += p[r];
        l_run = l_run * scale + lsub;
        m_run = m_new;
        // Phase C: pure-register PV
#pragma unroll
        for (int j = 0; j < 4; ++j) {
            float pr = p[(wave << 2) + j];
#pragma unroll
            for (int i = 0; i < 4; ++i) {
                acc[i].x += pr * e[j][i].x; acc[i].y += pr * e[j][i].y;
                acc[i].z += pr * e[j][i].z; acc[i].w += pr * e[j][i].w;
            }
        }
    }

    // cross-wave reduce: wave w's acc[i] covers d-slot i*64+lane
#pragma unroll
    for (int i = 0; i < 4; ++i) accbuf[wave * 256 + i * 64 + lane] = acc[i];
    __syncthreads();
    float4 tot = accbuf[t];
#pragma unroll
    for (int w = 1; w < 4; ++w) {
        float4 v = accbuf[w * 256 + t];
        tot.x += v.x; tot.y += v.y; tot.z += v.z; tot.w += v.w;
    }
    float4* cp = (float4*)(ctx_part + ((size_t)(b * SPLIT + chunk) << 10));
    cp[t] = tot;
    if (t == 0) {
        ml_part[(b * SPLIT + chunk) * 2]     = m_run;
        ml_part[(b * SPLIT + chunk) * 2 + 1] = l_run;
    }
}

// Combine SPLIT partials per batch; write ctx^T into concatT rows 0..1023.
__global__ __launch_bounds__(256) void k_reduce(const float* __restrict__ ctx_part,
                                                const float* __restrict__ ml_part,
                                                float* __restrict__ concatT,
                                                float* __restrict__ mlfinal) {
    int b = blockIdx.x, t = threadIdx.x;
    float M = -3.0e38f;
#pragma unroll
    for (int c = 0; c < SPLIT; ++c) M = fmaxf(M, ml_part[(b * SPLIT + c) * 2]);
    float L = 0.f;
    float4 acc = {0.f, 0.f, 0.f, 0.f};
#pragma unroll
    for (int c = 0; c < SPLIT; ++c) {
        float e = expf(ml_part[(b * SPLIT + c) * 2] - M);
        L += ml_part[(b * SPLIT + c) * 2 + 1] * e;
        const float4* cp = (const float4*)(ctx_part + ((size_t)(b * SPLIT + c) << 10));
        float4 v = cp[t];
        acc.x += e * v.x; acc.y += e * v.y; acc.z += e * v.z; acc.w += e * v.w;
    }
    float inv = 1.f / L;
    int d = t * 4;
    concatT[(d + 0) * BSZ + b] = acc.x * inv;
    concatT[(d + 1) * BSZ + b] = acc.y * inv;
    concatT[(d + 2) * BSZ + b] = acc.z * inv;
    concatT[(d + 3) * BSZ + b] = acc.w * inv;
    if (t == 0) { mlfinal[b * 2] = M; mlfinal[b * 2 + 1] = L; }
}

__global__ void k_attn(const float* __restrict__ scoresG,
                       const float* __restrict__ mlfinal,
                       float* __restrict__ outAttn) {
    int idx = blockIdx.x * 256 + threadIdx.x;  // [s][b]
    int b = idx & 63;
    float M = mlfinal[b * 2], L = mlfinal[b * 2 + 1];
    outAttn[idx] = expf(scoresG[idx] - M) / L;
}

// Partial out GEMM: grid (64 colgroups, KS2); 128-k chunks of the 2048-k dot.
__global__ __launch_bounds__(256) void k_out_part(const float* __restrict__ W2,
                                                  const float* __restrict__ concatT,
                                                  float* __restrict__ outpart) {
    __shared__ float tile[128 * 64];
    int t = threadIdx.x, lane = t & 63, wave = t >> 6;
    int k0 = blockIdx.y * 128;
    int c_base = blockIdx.x * 16 + (wave << 2);
    {
        const float4* src = (const float4*)(concatT + k0 * BSZ);
        float4* dst = (float4*)tile;
#pragma unroll
        for (int i = 0; i < 8; ++i) dst[t + i * 256] = src[t + i * 256];
    }
    __syncthreads();
    float acc[4] = {0.f, 0.f, 0.f, 0.f};
    for (int k = 0; k < 128; k += 4) {
        float v0 = tile[(k + 0) * 64 + lane];
        float v1 = tile[(k + 1) * 64 + lane];
        float v2 = tile[(k + 2) * 64 + lane];
        float v3 = tile[(k + 3) * 64 + lane];
#pragma unroll
        for (int oi = 0; oi < 4; ++oi) {
            float4 w = *(const float4*)&W2[(size_t)(c_base + oi) * (HID + DOUT) + k0 + k];
            acc[oi] += w.x * v0 + w.y * v1 + w.z * v2 + w.w * v3;
        }
    }
#pragma unroll
    for (int oi = 0; oi < 4; ++oi)
        outpart[((size_t)blockIdx.y * 64 + lane) * 1024 + c_base + oi] = acc[oi];
}

__global__ void k_out_reduce(const float* __restrict__ outpart, float* __restrict__ out) {
    int idx = blockIdx.x * 256 + threadIdx.x;  // b*1024 + o
    float s = 0.f;
#pragma unroll
    for (int ks = 0; ks < KS2; ++ks) s += outpart[(size_t)ks * 65536 + idx];
    out[idx] = tanhf(s);
}

extern "C" void kernel_launch(void* const* d_in, const int* in_sizes, int n_in,
                              void* d_out, int out_size, void* d_ws, size_t ws_size,
                              hipStream_t stream) {
    const float* hidden   = (const float*)d_in[0];
    const float* enc      = (const float*)d_in[1];
    const int*   src_lens = (const int*)d_in[2];
    const float* W1       = (const float*)d_in[3];
    const float* W2       = (const float*)d_in[4];
    float* out     = (float*)d_out;        // [64][1024]
    float* outAttn = out + 65536;          // [1024][64]

    float* ws       = (float*)d_ws;
    float* concatT  = ws;                  // [2048][64]
    float* x        = ws + 131072;         // [64][1024]
    float* scoresG  = ws + 196608;         // [1024][64]
    float* ctx_part = ws + 262144;         // [64][16][1024]
    float* ml_part  = ws + 1310720;        // [64][16][2]
    float* mlfinal  = ws + 1312768;        // [64][2]
    float* xpart    = ws + 1312896;        // [8][64][1024]
    float* outpart  = ws + 1837184;        // [16][64][1024]

    k_transpose_hidden<<<256, 256, 0, stream>>>(hidden, concatT);
    k_gemm_x_part<<<dim3(64, KS1), 256, 0, stream>>>(W1, concatT, xpart);
    k_x_reduce<<<256, 256, 0, stream>>>(xpart, x);
    k_score<<<dim3(SPLIT, BSZ), 256, 0, stream>>>(enc, x, src_lens, scoresG, ctx_part, ml_part);
    k_reduce<<<BSZ, 256, 0, stream>>>(ctx_part, ml_part, concatT, mlfinal);
    k_attn<<<256, 256, 0, stream>>>(scoresG, mlfinal, outAttn);
    k_out_part<<<dim3(64, KS2), 256, 0, stream>>>(W2, concatT, outpart);
    k_out_reduce<<<256, 256, 0, stream>>>(outpart, out);
}

// Round 3
// 93.627 us; speedup vs baseline: 2.8476x; 1.0699x over previous
//
#include <hip/hip_runtime.h>
#include <math.h>

// Problem constants
#define BSZ 64
#define SEQ 1024
#define HID 1024
#define DOUT 1024
#define SPLIT 16           // s-chunks per batch -> grid (16,64) for k_score
#define CHUNK (SEQ/SPLIT)  // 64 rows per block; 16 rows per wave

typedef float f32x4 __attribute__((ext_vector_type(4)));

// ws layout (floats):
//  x        [64][1024]       @ 0
//  scoresG  [1024][64]       @ 65536
//  ctxT     [1024][64]       @ 131072
//  ctx_part [64][16][1024]   @ 196608
//  ml_part  [64][16][2]      @ 1245184
//  xpart    [8][64][1024]    @ 1247360
//  outpart  [16][64][1024]   @ 1771648

// GEMV over hidden: computes x-partials (W1) AND out-partials for the
// hidden half of W2 (cols k>=1024), sharing one staged hidden tile.
// grid (128, 8): bx<64 -> x cols, bx>=64 -> out cols. by = 128-wide k-chunk.
__global__ __launch_bounds__(256) void k_gemv_hid(const float* __restrict__ hidden,
                                                  const float* __restrict__ W1,
                                                  const float* __restrict__ W2,
                                                  float* __restrict__ xpart,
                                                  float* __restrict__ outpart) {
    __shared__ float tile[128 * 65];   // [k][b], +1 pad
    int t = threadIdx.x, lane = t & 63, wave = t >> 6;
    int k0 = blockIdx.y * 128;
    // stage hidden[:, k0:k0+128] transposed
#pragma unroll
    for (int p = 0; p < 8; ++p) {
        int b = p * 8 + (t >> 5), l5 = t & 31;
        f32x4 h = *(const f32x4*)&hidden[b * 1024 + k0 + l5 * 4];
        tile[(l5 * 4 + 0) * 65 + b] = h.x;
        tile[(l5 * 4 + 1) * 65 + b] = h.y;
        tile[(l5 * 4 + 2) * 65 + b] = h.z;
        tile[(l5 * 4 + 3) * 65 + b] = h.w;
    }
    __syncthreads();
    bool isX = blockIdx.x < 64;
    int cg = isX ? blockIdx.x : blockIdx.x - 64;
    int c_base = cg * 16 + (wave << 2);
    const float* w0p = isX ? (W1 + (size_t)(c_base + 0) * 1024 + k0)
                           : (W2 + (size_t)(c_base + 0) * 2048 + 1024 + k0);
    size_t ldw = isX ? 1024 : 2048;
    float acc[4] = {0.f, 0.f, 0.f, 0.f};
    for (int k = 0; k < 128; k += 4) {
        float v0 = tile[(k + 0) * 65 + lane];
        float v1 = tile[(k + 1) * 65 + lane];
        float v2 = tile[(k + 2) * 65 + lane];
        float v3 = tile[(k + 3) * 65 + lane];
#pragma unroll
        for (int oi = 0; oi < 4; ++oi) {
            f32x4 w = *(const f32x4*)&w0p[oi * ldw + k];
            acc[oi] += w.x * v0 + w.y * v1 + w.z * v2 + w.w * v3;
        }
    }
    float* dst = isX ? (xpart + (size_t)blockIdx.y * 65536)
                     : (outpart + (size_t)(8 + blockIdx.y) * 65536);
#pragma unroll
    for (int oi = 0; oi < 4; ++oi)
        dst[(size_t)lane * 1024 + c_base + oi] = acc[oi];
}

__global__ void k_x_reduce(const float* __restrict__ xpart, float* __restrict__ x) {
    int idx = blockIdx.x * 256 + threadIdx.x;
    float s = 0.f;
#pragma unroll
    for (int ks = 0; ks < 8; ++ks) s += xpart[(size_t)ks * 65536 + idx];
    x[idx] = s;
}

// Barrier-free fused scores + mask + per-wave online softmax + ctx partials.
__global__ __launch_bounds__(256, 4) void k_score(const float* __restrict__ enc,
                                                  const float* __restrict__ x,
                                                  const int* __restrict__ src_lens,
                                                  float* __restrict__ scoresG,
                                                  float* __restrict__ ctx_part,
                                                  float* __restrict__ ml_part) {
    int b = blockIdx.y, chunk = blockIdx.x;
    int t = threadIdx.x, lane = t & 63, wave = t >> 6;
    __shared__ f32x4 accbuf[4 * 256];
    __shared__ float mbuf[4], lbuf[4];

    f32x4 xv[4];
    const f32x4* x4 = (const f32x4*)(x + b * HID);
#pragma unroll
    for (int i = 0; i < 4; ++i) xv[i] = x4[i * 64 + lane];
    int len = src_lens[b];
    int s_wave0 = chunk * CHUNK + wave * 16;
    const float* encb = enc + ((size_t)b << 20);

    float m_run = -3.0e38f, l_run = 0.f;
    f32x4 acc[4];
#pragma unroll
    for (int i = 0; i < 4; ++i) acc[i] = (f32x4)0.f;

#pragma unroll 1
    for (int g = 0; g < 4; ++g) {
        int sbase = s_wave0 + g * 4;
        f32x4 e[4][4];
#pragma unroll
        for (int j = 0; j < 4; ++j) {
            const f32x4* row4 = (const f32x4*)(encb + (size_t)(sbase + j) * DOUT);
#pragma unroll
            for (int i = 0; i < 4; ++i)
                e[j][i] = __builtin_nontemporal_load(row4 + i * 64 + lane);
        }
        float d0 = 0.f, d1 = 0.f, d2 = 0.f, d3 = 0.f;
#pragma unroll
        for (int i = 0; i < 4; ++i) {
            d0 += e[0][i].x * xv[i].x + e[0][i].y * xv[i].y + e[0][i].z * xv[i].z + e[0][i].w * xv[i].w;
            d1 += e[1][i].x * xv[i].x + e[1][i].y * xv[i].y + e[1][i].z * xv[i].z + e[1][i].w * xv[i].w;
            d2 += e[2][i].x * xv[i].x + e[2][i].y * xv[i].y + e[2][i].z * xv[i].z + e[2][i].w * xv[i].w;
            d3 += e[3][i].x * xv[i].x + e[3][i].y * xv[i].y + e[3][i].z * xv[i].z + e[3][i].w * xv[i].w;
        }
#pragma unroll
        for (int off = 32; off > 0; off >>= 1) {
            d0 += __shfl_xor(d0, off, 64);
            d1 += __shfl_xor(d1, off, 64);
            d2 += __shfl_xor(d2, off, 64);
            d3 += __shfl_xor(d3, off, 64);
        }
        // mask: invalid rows -> 0; any exact zero -> -1e10 (reference quirk)
        float v0 = (sbase + 0 < len) ? d0 : 0.f; if (v0 == 0.f) v0 = -1.0e10f;
        float v1 = (sbase + 1 < len) ? d1 : 0.f; if (v1 == 0.f) v1 = -1.0e10f;
        float v2 = (sbase + 2 < len) ? d2 : 0.f; if (v2 == 0.f) v2 = -1.0e10f;
        float v3 = (sbase + 3 < len) ? d3 : 0.f; if (v3 == 0.f) v3 = -1.0e10f;
        if (lane == 0) {
            scoresG[(sbase + 0) * BSZ + b] = v0;
            scoresG[(sbase + 1) * BSZ + b] = v1;
            scoresG[(sbase + 2) * BSZ + b] = v2;
            scoresG[(sbase + 3) * BSZ + b] = v3;
        }
        float msub = fmaxf(fmaxf(v0, v1), fmaxf(v2, v3));
        float m_new = fmaxf(m_run, msub);
        float scale = __expf(m_run - m_new);
        float p0 = __expf(v0 - m_new), p1 = __expf(v1 - m_new);
        float p2 = __expf(v2 - m_new), p3 = __expf(v3 - m_new);
        l_run = l_run * scale + (p0 + p1 + p2 + p3);
        m_run = m_new;
#pragma unroll
        for (int i = 0; i < 4; ++i)
            acc[i] = acc[i] * scale + p0 * e[0][i] + p1 * e[1][i] + p2 * e[2][i] + p3 * e[3][i];
    }

    // block merge (single barrier)
#pragma unroll
    for (int i = 0; i < 4; ++i) accbuf[wave * 256 + i * 64 + lane] = acc[i];
    if (lane == 0) { mbuf[wave] = m_run; lbuf[wave] = l_run; }
    __syncthreads();
    float M = fmaxf(fmaxf(mbuf[0], mbuf[1]), fmaxf(mbuf[2], mbuf[3]));
    float w0 = __expf(mbuf[0] - M), w1 = __expf(mbuf[1] - M);
    float w2 = __expf(mbuf[2] - M), w3 = __expf(mbuf[3] - M);
    f32x4 tot = accbuf[t] * w0 + accbuf[256 + t] * w1 + accbuf[512 + t] * w2 + accbuf[768 + t] * w3;
    ((f32x4*)(ctx_part + ((size_t)(b * SPLIT + chunk) << 10)))[t] = tot;
    if (t == 0) {
        float Lt = lbuf[0] * w0 + lbuf[1] * w1 + lbuf[2] * w2 + lbuf[3] * w3;
        ml_part[(b * SPLIT + chunk) * 2] = M;
        ml_part[(b * SPLIT + chunk) * 2 + 1] = Lt;
    }
}

// Per-batch combine + attn normalize. grid 64.
__global__ __launch_bounds__(256) void k_reduce_attn(const float* __restrict__ ctx_part,
                                                     const float* __restrict__ ml_part,
                                                     const float* __restrict__ scoresG,
                                                     float* __restrict__ ctxT,
                                                     float* __restrict__ outAttn) {
    int b = blockIdx.x, t = threadIdx.x;
    float M = -3.0e38f;
#pragma unroll
    for (int c = 0; c < SPLIT; ++c) M = fmaxf(M, ml_part[(b * SPLIT + c) * 2]);
    float L = 0.f;
    f32x4 acc = (f32x4)0.f;
#pragma unroll
    for (int c = 0; c < SPLIT; ++c) {
        float e = __expf(ml_part[(b * SPLIT + c) * 2] - M);
        L += ml_part[(b * SPLIT + c) * 2 + 1] * e;
        f32x4 v = ((const f32x4*)(ctx_part + ((size_t)(b * SPLIT + c) << 10)))[t];
        acc += e * v;
    }
    float inv = 1.f / L;
    int d = t * 4;
    ctxT[(d + 0) * BSZ + b] = acc.x * inv;
    ctxT[(d + 1) * BSZ + b] = acc.y * inv;
    ctxT[(d + 2) * BSZ + b] = acc.z * inv;
    ctxT[(d + 3) * BSZ + b] = acc.w * inv;
#pragma unroll
    for (int s = 0; s < 4; ++s) {
        int si = s * 256 + t;
        outAttn[si * BSZ + b] = __expf(scoresG[si * BSZ + b] - M) * inv;
    }
}

// ctx half of the output GEMM: grid (64, 8), k0 = by*128 over ctxT[d][b].
__global__ __launch_bounds__(256) void k_out_part(const float* __restrict__ W2,
                                                  const float* __restrict__ ctxT,
                                                  float* __restrict__ outpart) {
    __shared__ float tile[128 * 64];
    int t = threadIdx.x, lane = t & 63, wave = t >> 6;
    int k0 = blockIdx.y * 128;
    int c_base = blockIdx.x * 16 + (wave << 2);
    {
        const f32x4* src = (const f32x4*)(ctxT + k0 * 64);
        f32x4* dst = (f32x4*)tile;
#pragma unroll
        for (int i = 0; i < 8; ++i) dst[t + i * 256] = src[t + i * 256];
    }
    __syncthreads();
    float acc[4] = {0.f, 0.f, 0.f, 0.f};
    for (int k = 0; k < 128; k += 4) {
        float v0 = tile[(k + 0) * 64 + lane];
        float v1 = tile[(k + 1) * 64 + lane];
        float v2 = tile[(k + 2) * 64 + lane];
        float v3 = tile[(k + 3) * 64 + lane];
#pragma unroll
        for (int oi = 0; oi < 4; ++oi) {
            f32x4 w = *(const f32x4*)&W2[(size_t)(c_base + oi) * 2048 + k0 + k];
            acc[oi] += w.x * v0 + w.y * v1 + w.z * v2 + w.w * v3;
        }
    }
#pragma unroll
    for (int oi = 0; oi < 4; ++oi)
        outpart[(size_t)blockIdx.y * 65536 + (size_t)lane * 1024 + c_base + oi] = acc[oi];
}

__global__ void k_out_reduce(const float* __restrict__ outpart, float* __restrict__ out) {
    int idx = blockIdx.x * 256 + threadIdx.x;
    float s = 0.f;
#pragma unroll
    for (int ks = 0; ks < 16; ++ks) s += outpart[(size_t)ks * 65536 + idx];
    out[idx] = tanhf(s);
}

extern "C" void kernel_launch(void* const* d_in, const int* in_sizes, int n_in,
                              void* d_out, int out_size, void* d_ws, size_t ws_size,
                              hipStream_t stream) {
    const float* hidden   = (const float*)d_in[0];
    const float* enc      = (const float*)d_in[1];
    const int*   src_lens = (const int*)d_in[2];
    const float* W1       = (const float*)d_in[3];
    const float* W2       = (const float*)d_in[4];
    float* out     = (float*)d_out;        // [64][1024]
    float* outAttn = out + 65536;          // [1024][64]

    float* ws       = (float*)d_ws;
    float* x        = ws;                  // [64][1024]
    float* scoresG  = ws + 65536;          // [1024][64]
    float* ctxT     = ws + 131072;         // [1024][64]
    float* ctx_part = ws + 196608;         // [64][16][1024]
    float* ml_part  = ws + 1245184;        // [64][16][2]
    float* xpart    = ws + 1247360;        // [8][64][1024]
    float* outpart  = ws + 1771648;        // [16][64][1024]

    k_gemv_hid<<<dim3(128, 8), 256, 0, stream>>>(hidden, W1, W2, xpart, outpart);
    k_x_reduce<<<256, 256, 0, stream>>>(xpart, x);
    k_score<<<dim3(SPLIT, BSZ), 256, 0, stream>>>(enc, x, src_lens, scoresG, ctx_part, ml_part);
    k_reduce_attn<<<BSZ, 256, 0, stream>>>(ctx_part, ml_part, scoresG, ctxT, outAttn);
    k_out_part<<<dim3(64, 8), 256, 0, stream>>>(W2, ctxT, outpart);
    k_out_reduce<<<256, 256, 0, stream>>>(outpart, out);
}

// Round 4
// 72.018 us; speedup vs baseline: 3.7019x; 1.3000x over previous
//
#include <hip/hip_runtime.h>
#include <math.h>

// Problem constants
#define BSZ 64
#define SEQ 1024
#define HID 1024
#define DOUT 1024
#define SPLIT 16           // s-chunks per batch -> grid (16,64) for k_score
#define CHUNK (SEQ/SPLIT)  // 64 rows per block; 16 rows per wave

typedef float f32x4 __attribute__((ext_vector_type(4)));

// ws layout (floats):
//  scoresG  [1024][64]       @ 0
//  ctxT     [1024][64]       @ 65536
//  ctx_part [64][16][1024]   @ 131072
//  ml_part  [64][16][2]      @ 1179648
//  xpart    [8][64][1024]    @ 1181696
//  outpart  [16][64][1024]   @ 1705984

// GEMV over hidden: x-partials (W1) AND out-partials for the hidden half of
// W2 (cols k>=1024), sharing one staged hidden tile.
// grid (128, 8): bx<64 -> x cols, bx>=64 -> out cols. by = 128-wide k-chunk.
__global__ __launch_bounds__(256) void k_gemv_hid(const float* __restrict__ hidden,
                                                  const float* __restrict__ W1,
                                                  const float* __restrict__ W2,
                                                  float* __restrict__ xpart,
                                                  float* __restrict__ outpart) {
    __shared__ float tile[128 * 65];   // [k][b], +1 pad
    int t = threadIdx.x, lane = t & 63, wave = t >> 6;
    int k0 = blockIdx.y * 128;
#pragma unroll
    for (int p = 0; p < 8; ++p) {
        int b = p * 8 + (t >> 5), l5 = t & 31;
        f32x4 h = *(const f32x4*)&hidden[b * 1024 + k0 + l5 * 4];
        tile[(l5 * 4 + 0) * 65 + b] = h.x;
        tile[(l5 * 4 + 1) * 65 + b] = h.y;
        tile[(l5 * 4 + 2) * 65 + b] = h.z;
        tile[(l5 * 4 + 3) * 65 + b] = h.w;
    }
    __syncthreads();
    bool isX = blockIdx.x < 64;
    int cg = isX ? blockIdx.x : blockIdx.x - 64;
    int c_base = cg * 16 + (wave << 2);
    const float* w0p = isX ? (W1 + (size_t)c_base * 1024 + k0)
                           : (W2 + (size_t)c_base * 2048 + 1024 + k0);
    size_t ldw = isX ? 1024 : 2048;
    float acc[4] = {0.f, 0.f, 0.f, 0.f};
    for (int k = 0; k < 128; k += 4) {
        float v0 = tile[(k + 0) * 65 + lane];
        float v1 = tile[(k + 1) * 65 + lane];
        float v2 = tile[(k + 2) * 65 + lane];
        float v3 = tile[(k + 3) * 65 + lane];
#pragma unroll
        for (int oi = 0; oi < 4; ++oi) {
            f32x4 w = *(const f32x4*)&w0p[oi * ldw + k];
            acc[oi] += w.x * v0 + w.y * v1 + w.z * v2 + w.w * v3;
        }
    }
    float* dst = isX ? (xpart + (size_t)blockIdx.y * 65536)
                     : (outpart + (size_t)(8 + blockIdx.y) * 65536);
#pragma unroll
    for (int oi = 0; oi < 4; ++oi)
        dst[(size_t)lane * 1024 + c_base + oi] = acc[oi];
}

// Barrier-free fused scores + mask + per-wave online softmax + ctx partials.
// Skips entire 4-row groups with sbase >= len (their softmax weight is exactly 0).
__global__ __launch_bounds__(256, 4) void k_score(const float* __restrict__ enc,
                                                  const float* __restrict__ xpart,
                                                  const int* __restrict__ src_lens,
                                                  float* __restrict__ scoresG,
                                                  float* __restrict__ ctx_part,
                                                  float* __restrict__ ml_part) {
    int b = blockIdx.y, chunk = blockIdx.x;
    int t = threadIdx.x, lane = t & 63, wave = t >> 6;
    __shared__ f32x4 accbuf[4 * 256];
    __shared__ float mbuf[4], lbuf[4];

    // x[b][:] = sum of the 8 K-partials (xpart is L2-hot, 2 MB)
    f32x4 xv[4];
#pragma unroll
    for (int i = 0; i < 4; ++i) {
        f32x4 s = (f32x4)0.f;
#pragma unroll
        for (int ks = 0; ks < 8; ++ks)
            s += ((const f32x4*)(xpart + (size_t)ks * 65536 + (size_t)b * 1024))[i * 64 + lane];
        xv[i] = s;
    }
    int len = src_lens[b];
    int s_wave0 = chunk * CHUNK + wave * 16;
    const float* encb = enc + ((size_t)b << 20);

    float m_run = -3.0e38f, l_run = 0.f;
    f32x4 acc[4];
#pragma unroll
    for (int i = 0; i < 4; ++i) acc[i] = (f32x4)0.f;

#pragma unroll 1
    for (int g = 0; g < 4; ++g) {
        int sbase = s_wave0 + g * 4;
        if (sbase >= len) {   // fully-masked group: weight underflows to 0, skip loads
            if (lane == 0) {
#pragma unroll
                for (int j = 0; j < 4; ++j) scoresG[(sbase + j) * BSZ + b] = -1.0e10f;
            }
            continue;
        }
        f32x4 e[4][4];
#pragma unroll
        for (int j = 0; j < 4; ++j) {
            const f32x4* row4 = (const f32x4*)(encb + (size_t)(sbase + j) * DOUT);
#pragma unroll
            for (int i = 0; i < 4; ++i) e[j][i] = row4[i * 64 + lane];
        }
        float d0 = 0.f, d1 = 0.f, d2 = 0.f, d3 = 0.f;
#pragma unroll
        for (int i = 0; i < 4; ++i) {
            d0 += e[0][i].x * xv[i].x + e[0][i].y * xv[i].y + e[0][i].z * xv[i].z + e[0][i].w * xv[i].w;
            d1 += e[1][i].x * xv[i].x + e[1][i].y * xv[i].y + e[1][i].z * xv[i].z + e[1][i].w * xv[i].w;
            d2 += e[2][i].x * xv[i].x + e[2][i].y * xv[i].y + e[2][i].z * xv[i].z + e[2][i].w * xv[i].w;
            d3 += e[3][i].x * xv[i].x + e[3][i].y * xv[i].y + e[3][i].z * xv[i].z + e[3][i].w * xv[i].w;
        }
#pragma unroll
        for (int off = 32; off > 0; off >>= 1) {
            d0 += __shfl_xor(d0, off, 64);
            d1 += __shfl_xor(d1, off, 64);
            d2 += __shfl_xor(d2, off, 64);
            d3 += __shfl_xor(d3, off, 64);
        }
        // mask: invalid rows -> 0; any exact zero -> -1e10 (reference quirk)
        float v0 = (sbase + 0 < len) ? d0 : 0.f; if (v0 == 0.f) v0 = -1.0e10f;
        float v1 = (sbase + 1 < len) ? d1 : 0.f; if (v1 == 0.f) v1 = -1.0e10f;
        float v2 = (sbase + 2 < len) ? d2 : 0.f; if (v2 == 0.f) v2 = -1.0e10f;
        float v3 = (sbase + 3 < len) ? d3 : 0.f; if (v3 == 0.f) v3 = -1.0e10f;
        if (lane == 0) {
            scoresG[(sbase + 0) * BSZ + b] = v0;
            scoresG[(sbase + 1) * BSZ + b] = v1;
            scoresG[(sbase + 2) * BSZ + b] = v2;
            scoresG[(sbase + 3) * BSZ + b] = v3;
        }
        float msub = fmaxf(fmaxf(v0, v1), fmaxf(v2, v3));
        float m_new = fmaxf(m_run, msub);
        float scale = __expf(m_run - m_new);
        float p0 = __expf(v0 - m_new), p1 = __expf(v1 - m_new);
        float p2 = __expf(v2 - m_new), p3 = __expf(v3 - m_new);
        l_run = l_run * scale + (p0 + p1 + p2 + p3);
        m_run = m_new;
#pragma unroll
        for (int i = 0; i < 4; ++i)
            acc[i] = acc[i] * scale + p0 * e[0][i] + p1 * e[1][i] + p2 * e[2][i] + p3 * e[3][i];
    }

    // block merge (single barrier)
#pragma unroll
    for (int i = 0; i < 4; ++i) accbuf[wave * 256 + i * 64 + lane] = acc[i];
    if (lane == 0) { mbuf[wave] = m_run; lbuf[wave] = l_run; }
    __syncthreads();
    float M = fmaxf(fmaxf(mbuf[0], mbuf[1]), fmaxf(mbuf[2], mbuf[3]));
    float w0 = __expf(mbuf[0] - M), w1 = __expf(mbuf[1] - M);
    float w2 = __expf(mbuf[2] - M), w3 = __expf(mbuf[3] - M);
    f32x4 tot = accbuf[t] * w0 + accbuf[256 + t] * w1 + accbuf[512 + t] * w2 + accbuf[768 + t] * w3;
    ((f32x4*)(ctx_part + ((size_t)(b * SPLIT + chunk) << 10)))[t] = tot;
    if (t == 0) {
        float Lt = lbuf[0] * w0 + lbuf[1] * w1 + lbuf[2] * w2 + lbuf[3] * w3;
        ml_part[(b * SPLIT + chunk) * 2] = M;
        ml_part[(b * SPLIT + chunk) * 2 + 1] = Lt;
    }
}

// Per-batch combine + attn normalize. grid 256: b = bid>>2, quarter = bid&3.
__global__ __launch_bounds__(256) void k_reduce_attn(const float* __restrict__ ctx_part,
                                                     const float* __restrict__ ml_part,
                                                     const float* __restrict__ scoresG,
                                                     float* __restrict__ ctxT,
                                                     float* __restrict__ outAttn) {
    int b = blockIdx.x >> 2, q = blockIdx.x & 3, t = threadIdx.x;
    float M = -3.0e38f;
#pragma unroll
    for (int c = 0; c < SPLIT; ++c) M = fmaxf(M, ml_part[(b * SPLIT + c) * 2]);
    float L = 0.f;
    float wgt[SPLIT];
#pragma unroll
    for (int c = 0; c < SPLIT; ++c) {
        float e = __expf(ml_part[(b * SPLIT + c) * 2] - M);
        wgt[c] = e;
        L += ml_part[(b * SPLIT + c) * 2 + 1] * e;
    }
    float inv = 1.f / L;
    int d = q * 256 + t;
    float acc = 0.f;
#pragma unroll
    for (int c = 0; c < SPLIT; ++c)
        acc += wgt[c] * ctx_part[((size_t)(b * SPLIT + c) << 10) + d];
    ctxT[d * BSZ + b] = acc * inv;
    outAttn[d * BSZ + b] = __expf(scoresG[d * BSZ + b] - M) * inv;  // d doubles as s
}

// ctx half of the output GEMM: grid (64, 8), k0 = by*128 over ctxT[d][b].
__global__ __launch_bounds__(256) void k_out_part(const float* __restrict__ W2,
                                                  const float* __restrict__ ctxT,
                                                  float* __restrict__ outpart) {
    __shared__ float tile[128 * 64];
    int t = threadIdx.x, lane = t & 63, wave = t >> 6;
    int k0 = blockIdx.y * 128;
    int c_base = blockIdx.x * 16 + (wave << 2);
    {
        const f32x4* src = (const f32x4*)(ctxT + k0 * 64);
        f32x4* dst = (f32x4*)tile;
#pragma unroll
        for (int i = 0; i < 8; ++i) dst[t + i * 256] = src[t + i * 256];
    }
    __syncthreads();
    float acc[4] = {0.f, 0.f, 0.f, 0.f};
    for (int k = 0; k < 128; k += 4) {
        float v0 = tile[(k + 0) * 64 + lane];
        float v1 = tile[(k + 1) * 64 + lane];
        float v2 = tile[(k + 2) * 64 + lane];
        float v3 = tile[(k + 3) * 64 + lane];
#pragma unroll
        for (int oi = 0; oi < 4; ++oi) {
            f32x4 w = *(const f32x4*)&W2[(size_t)(c_base + oi) * 2048 + k0 + k];
            acc[oi] += w.x * v0 + w.y * v1 + w.z * v2 + w.w * v3;
        }
    }
#pragma unroll
    for (int oi = 0; oi < 4; ++oi)
        outpart[(size_t)blockIdx.y * 65536 + (size_t)lane * 1024 + c_base + oi] = acc[oi];
}

__global__ void k_out_reduce(const float* __restrict__ outpart, float* __restrict__ out) {
    int idx = blockIdx.x * 256 + threadIdx.x;
    float s = 0.f;
#pragma unroll
    for (int ks = 0; ks < 16; ++ks) s += outpart[(size_t)ks * 65536 + idx];
    out[idx] = tanhf(s);
}

extern "C" void kernel_launch(void* const* d_in, const int* in_sizes, int n_in,
                              void* d_out, int out_size, void* d_ws, size_t ws_size,
                              hipStream_t stream) {
    const float* hidden   = (const float*)d_in[0];
    const float* enc      = (const float*)d_in[1];
    const int*   src_lens = (const int*)d_in[2];
    const float* W1       = (const float*)d_in[3];
    const float* W2       = (const float*)d_in[4];
    float* out     = (float*)d_out;        // [64][1024]
    float* outAttn = out + 65536;          // [1024][64]

    float* ws       = (float*)d_ws;
    float* scoresG  = ws;                  // [1024][64]
    float* ctxT     = ws + 65536;          // [1024][64]
    float* ctx_part = ws + 131072;         // [64][16][1024]
    float* ml_part  = ws + 1179648;        // [64][16][2]
    float* xpart    = ws + 1181696;        // [8][64][1024]
    float* outpart  = ws + 1705984;        // [16][64][1024]

    k_gemv_hid<<<dim3(128, 8), 256, 0, stream>>>(hidden, W1, W2, xpart, outpart);
    k_score<<<dim3(SPLIT, BSZ), 256, 0, stream>>>(enc, xpart, src_lens, scoresG, ctx_part, ml_part);
    k_reduce_attn<<<256, 256, 0, stream>>>(ctx_part, ml_part, scoresG, ctxT, outAttn);
    k_out_part<<<dim3(64, 8), 256, 0, stream>>>(W2, ctxT, outpart);
    k_out_reduce<<<256, 256, 0, stream>>>(outpart, out);
}